// Round 1
// baseline (326.221 us; speedup 1.0000x reference)
//
#include <hip/hip_runtime.h>
#include <math.h>

// Problem: GCNConv forward with spectral-norm weight scaling.
// x[N,128] f32, edge_index[2,E] int32, W[128,64] f32, bias[64] f32,
// ew[E] f32, u[128] f32  ->  out[N,64] f32.
// N = 100000, E = 600000 (read from in_sizes for robustness).

#define IN_DIM 128
#define OUT_DIM 64
#define RPB 32   // rows per block in the GEMM

// ---------------------------------------------------------------------------
// K1: sigma = ||W v||^2 / (||W v|| + eps), v = (W^T u)/(||W^T u|| + eps).
// Single block, 128 threads. Writes inv_sigma = 1/sigma.
// ---------------------------------------------------------------------------
__global__ __launch_bounds__(128) void sigma_kernel(const float* __restrict__ W,
                                                    const float* __restrict__ u,
                                                    float* __restrict__ inv_sigma) {
    __shared__ float v[OUT_DIM];
    __shared__ float red[128];
    const int t = threadIdx.x;

    // tv[j] = sum_i W[i][j] * u[i]   (j = t for t < 64)
    float tv = 0.f;
    if (t < OUT_DIM) {
        #pragma unroll 4
        for (int i = 0; i < IN_DIM; ++i) tv += W[i * OUT_DIM + t] * u[i];
    }
    red[t] = (t < OUT_DIM) ? tv * tv : 0.f;
    __syncthreads();
    for (int s = 64; s > 0; s >>= 1) {
        if (t < s) red[t] += red[t + s];
        __syncthreads();
    }
    const float nv = sqrtf(red[0]) + 1e-12f;
    __syncthreads();
    if (t < OUT_DIM) v[t] = tv / nv;
    __syncthreads();

    // wv[i] = sum_j W[i][j] * v[j]   (i = t, all 128 threads)
    float wv = 0.f;
    #pragma unroll 4
    for (int j = 0; j < OUT_DIM; ++j) wv += W[t * OUT_DIM + j] * v[j];
    red[t] = wv * wv;
    __syncthreads();
    for (int s = 64; s > 0; s >>= 1) {
        if (t < s) red[t] += red[t + s];
        __syncthreads();
    }
    if (t == 0) {
        const float s2 = red[0];
        const float sn = sqrtf(s2);
        const float sigma = s2 / (sn + 1e-12f);
        inv_sigma[0] = 1.0f / sigma;
    }
}

// ---------------------------------------------------------------------------
// K2: w[e] = sigmoid(ew[e]); deg[col[e]] += w[e]  (deg pre-zeroed by memset)
// ---------------------------------------------------------------------------
__global__ __launch_bounds__(256) void edge_w_deg(const int* __restrict__ ei,
                                                  const float* __restrict__ ew,
                                                  float* __restrict__ wbuf,
                                                  float* __restrict__ deg,
                                                  int E) {
    const int e = blockIdx.x * 256 + threadIdx.x;
    if (e >= E) return;
    const float w = 1.f / (1.f + expf(-ew[e]));
    wbuf[e] = w;
    const int col = ei[E + e];
    atomicAdd(&deg[col], w);
}

// ---------------------------------------------------------------------------
// K3: xp = x @ (W * inv_sigma);  out = xp * (1/(deg+1)) + bias
// Block: 256 threads = 4 waves; each wave owns 8 rows, lane = output column.
// LDS: scaled W (32 KB) + x tile (16 KB) -> 48 KB, ~3 blocks/CU.
// ---------------------------------------------------------------------------
__global__ __launch_bounds__(256) void gemm_self(const float* __restrict__ x,
                                                 const float* __restrict__ W,
                                                 const float* __restrict__ bias,
                                                 const float* __restrict__ inv_sigma_p,
                                                 const float* __restrict__ deg,
                                                 float* __restrict__ xp,
                                                 float* __restrict__ out,
                                                 int N) {
    __shared__ float Wl[IN_DIM * OUT_DIM];   // 8192 floats
    __shared__ float xs[RPB * IN_DIM];       // 4096 floats

    const int t = threadIdx.x;
    const float isg = inv_sigma_p[0];

    // Load + scale W into LDS (coalesced, 32 elems/thread)
    for (int i = t; i < IN_DIM * OUT_DIM; i += 256) Wl[i] = W[i] * isg;

    // Load x tile (rows r0 .. r0+RPB-1), float4 vectorized
    const int r0 = blockIdx.x * RPB;
    const int nrow = min(RPB, N - r0);
    const float4* x4 = (const float4*)(x + (size_t)r0 * IN_DIM);
    float4* xs4 = (float4*)xs;
    const int nvec = nrow * IN_DIM / 4;
    for (int i = t; i < nvec; i += 256) xs4[i] = x4[i];
    __syncthreads();

    const int c = t & 63;        // output column (lane)
    const int wv = t >> 6;       // wave id 0..3
    const int rbase = wv * 8;    // 8 rows per wave

    float acc[8] = {0.f, 0.f, 0.f, 0.f, 0.f, 0.f, 0.f, 0.f};
    for (int k = 0; k < IN_DIM; k += 4) {
        const float w0 = Wl[(k + 0) * OUT_DIM + c];
        const float w1 = Wl[(k + 1) * OUT_DIM + c];
        const float w2 = Wl[(k + 2) * OUT_DIM + c];
        const float w3 = Wl[(k + 3) * OUT_DIM + c];
        #pragma unroll
        for (int rr = 0; rr < 8; ++rr) {
            const float4 xv = *(const float4*)&xs[(rbase + rr) * IN_DIM + k];
            acc[rr] += xv.x * w0 + xv.y * w1 + xv.z * w2 + xv.w * w3;
        }
    }

    #pragma unroll
    for (int rr = 0; rr < 8; ++rr) {
        const int row = r0 + rbase + rr;
        if (row < N) {
            const float dinv = 1.f / (deg[row] + 1.f);
            const float val = acc[rr];
            xp[(size_t)row * OUT_DIM + c] = val;
            out[(size_t)row * OUT_DIM + c] = val * dinv + bias[c];
        }
    }
}

// ---------------------------------------------------------------------------
// K4: edge scatter. One 64-lane wave per edge, lane = column.
// out[col] += xp[row] * (rsqrt(deg[row]+1) * w * rsqrt(deg[col]+1))
// ---------------------------------------------------------------------------
__global__ __launch_bounds__(256) void scatter_edges(const int* __restrict__ ei,
                                                     const float* __restrict__ wbuf,
                                                     const float* __restrict__ deg,
                                                     const float* __restrict__ xp,
                                                     float* __restrict__ out,
                                                     int E) {
    const long long gid = (long long)blockIdx.x * 256 + threadIdx.x;
    const int e = (int)(gid >> 6);
    const int lane = (int)(gid & 63);
    if (e >= E) return;
    const int row = ei[e];
    const int col = ei[E + e];
    const float w = wbuf[e];
    const float nrm = rsqrtf(deg[row] + 1.f) * w * rsqrtf(deg[col] + 1.f);
    const float val = xp[(size_t)row * OUT_DIM + lane] * nrm;
    atomicAdd(&out[(size_t)col * OUT_DIM + lane], val);
}

// ---------------------------------------------------------------------------
extern "C" void kernel_launch(void* const* d_in, const int* in_sizes, int n_in,
                              void* d_out, int out_size, void* d_ws, size_t ws_size,
                              hipStream_t stream) {
    const float* x    = (const float*)d_in[0];
    const int*   ei   = (const int*)d_in[1];
    const float* W    = (const float*)d_in[2];
    const float* bias = (const float*)d_in[3];
    const float* ew   = (const float*)d_in[4];
    const float* u    = (const float*)d_in[5];
    float* out = (float*)d_out;

    const int N = in_sizes[0] / IN_DIM;   // 100000
    const int E = in_sizes[4];            // 600000

    // Workspace layout (byte offsets):
    //   [0]                 inv_sigma (1 float)
    //   [1024]              wbuf[E]
    //   [1024 + 4E]         deg[N]
    //   [1024 + 4E + 4N]    xp[N*64]   (16B-aligned for these sizes)
    char* ws = (char*)d_ws;
    float* inv_sigma = (float*)ws;
    float* wbuf = (float*)(ws + 1024);
    float* deg  = (float*)(ws + 1024 + (size_t)E * 4);
    float* xp   = (float*)(ws + 1024 + (size_t)E * 4 + (size_t)N * 4);

    hipMemsetAsync(deg, 0, (size_t)N * sizeof(float), stream);
    sigma_kernel<<<1, 128, 0, stream>>>(W, u, inv_sigma);
    edge_w_deg<<<(E + 255) / 256, 256, 0, stream>>>(ei, ew, wbuf, deg, E);
    gemm_self<<<(N + RPB - 1) / RPB, 256, 0, stream>>>(x, W, bias, inv_sigma, deg, xp, out, N);
    scatter_edges<<<(int)(((long long)E * 64 + 255) / 256), 256, 0, stream>>>(ei, wbuf, deg, xp, out, E);
}

// Round 2
// 269.081 us; speedup vs baseline: 1.2124x; 1.2124x over previous
//
#include <hip/hip_runtime.h>
#include <math.h>

// GCNConv forward with spectral-norm weight scaling, CSR-gather formulation.
// x[N,128] f32, edge_index[2,E] int, W[128,64] f32, bias[64] f32,
// ew[E] f32, u[128] f32  ->  out[N,64] f32.   N=100000, E=600000.

#define IN_DIM 128
#define OUT_DIM 64

// ---------------------------------------------------------------------------
// K1: inv_sigma = 1/sigma, sigma from one power-iteration step.
// ---------------------------------------------------------------------------
__global__ __launch_bounds__(128) void sigma_kernel(const float* __restrict__ W,
                                                    const float* __restrict__ u,
                                                    float* __restrict__ inv_sigma) {
    __shared__ float v[OUT_DIM];
    __shared__ float red[128];
    const int t = threadIdx.x;

    float tv = 0.f;
    if (t < OUT_DIM) {
        #pragma unroll 4
        for (int i = 0; i < IN_DIM; ++i) tv += W[i * OUT_DIM + t] * u[i];
    }
    red[t] = (t < OUT_DIM) ? tv * tv : 0.f;
    __syncthreads();
    for (int s = 64; s > 0; s >>= 1) {
        if (t < s) red[t] += red[t + s];
        __syncthreads();
    }
    const float nv = sqrtf(red[0]) + 1e-12f;
    __syncthreads();
    if (t < OUT_DIM) v[t] = tv / nv;
    __syncthreads();

    float wv = 0.f;
    #pragma unroll 4
    for (int j = 0; j < OUT_DIM; ++j) wv += W[t * OUT_DIM + j] * v[j];
    red[t] = wv * wv;
    __syncthreads();
    for (int s = 64; s > 0; s >>= 1) {
        if (t < s) red[t] += red[t + s];
        __syncthreads();
    }
    if (t == 0) {
        const float s2 = red[0];
        const float sn = sqrtf(s2);
        const float sigma = s2 / (sn + 1e-12f);
        inv_sigma[0] = 1.0f / sigma;
    }
}

// ---------------------------------------------------------------------------
// K2: per-edge: w=sigmoid(ew); deg[col]+=w; cnt[col]+=1
// ---------------------------------------------------------------------------
__global__ __launch_bounds__(256) void edge_prep(const int* __restrict__ ei,
                                                 const float* __restrict__ ew,
                                                 float* __restrict__ deg,
                                                 int* __restrict__ cnt,
                                                 int E) {
    const int e = blockIdx.x * 256 + threadIdx.x;
    if (e >= E) return;
    const float w = 1.f / (1.f + expf(-ew[e]));
    const int col = ei[E + e];
    atomicAdd(&deg[col], w);
    atomicAdd(&cnt[col], 1);
}

// ---------------------------------------------------------------------------
// K3: xp = x @ (W * inv_sigma). Register-blocked: thread = 4 rows x 4 cols.
// Block 256 = 4 waves; wave covers 16 rows x 64 cols; block = 64 rows.
// W (scaled) lives in LDS; x read directly from global (float4, lane-shared).
// ---------------------------------------------------------------------------
__global__ __launch_bounds__(256) void gemm_xp(const float* __restrict__ x,
                                               const float* __restrict__ W,
                                               const float* __restrict__ inv_sigma_p,
                                               float* __restrict__ xp,
                                               int N) {
    __shared__ float Wl[IN_DIM * OUT_DIM];   // 32 KB
    const int t = threadIdx.x;
    const float isg = inv_sigma_p[0];

    // load + scale W, float4 vectorized
    const float4* W4 = (const float4*)W;
    float4* Wl4 = (float4*)Wl;
    #pragma unroll
    for (int i = t; i < IN_DIM * OUT_DIM / 4; i += 256) {
        float4 wv = W4[i];
        wv.x *= isg; wv.y *= isg; wv.z *= isg; wv.w *= isg;
        Wl4[i] = wv;
    }
    __syncthreads();

    const int wave = t >> 6;
    const int lane = t & 63;
    const int rg = lane >> 4;     // 0..3 row group
    const int cg = lane & 15;     // 0..15 col group (cols 4cg..4cg+3)
    const int rowBase = blockIdx.x * 64 + wave * 16 + rg * 4;

    float4 acc[4];
    #pragma unroll
    for (int r = 0; r < 4; ++r) acc[r] = make_float4(0.f, 0.f, 0.f, 0.f);

    const float4* xg = (const float4*)x;
    #pragma unroll 4
    for (int kc = 0; kc < IN_DIM / 4; ++kc) {
        float4 wv0 = Wl4[(4 * kc + 0) * 16 + cg];
        float4 wv1 = Wl4[(4 * kc + 1) * 16 + cg];
        float4 wv2 = Wl4[(4 * kc + 2) * 16 + cg];
        float4 wv3 = Wl4[(4 * kc + 3) * 16 + cg];
        #pragma unroll
        for (int r = 0; r < 4; ++r) {
            const int row = min(rowBase + r, N - 1);
            const float4 xv = xg[(size_t)row * (IN_DIM / 4) + kc];
            acc[r].x += xv.x * wv0.x + xv.y * wv1.x + xv.z * wv2.x + xv.w * wv3.x;
            acc[r].y += xv.x * wv0.y + xv.y * wv1.y + xv.z * wv2.y + xv.w * wv3.y;
            acc[r].z += xv.x * wv0.z + xv.y * wv1.z + xv.z * wv2.z + xv.w * wv3.z;
            acc[r].w += xv.x * wv0.w + xv.y * wv1.w + xv.z * wv2.w + xv.w * wv3.w;
        }
    }

    float4* xp4 = (float4*)xp;
    #pragma unroll
    for (int r = 0; r < 4; ++r) {
        const int row = rowBase + r;
        if (row < N) xp4[(size_t)row * 16 + cg] = acc[r];
    }
}

// ---------------------------------------------------------------------------
// Scan kernels: exclusive prefix over cnt[N] -> pos[N]. 1024 items/block.
// ---------------------------------------------------------------------------
__global__ __launch_bounds__(256) void scan_a(const int* __restrict__ cnt,
                                              int* __restrict__ pos,
                                              int* __restrict__ btot,
                                              int N) {
    __shared__ int s[256];
    const int t = threadIdx.x;
    const int i0 = blockIdx.x * 1024 + t * 4;
    int v[4]; int sum = 0;
    #pragma unroll
    for (int j = 0; j < 4; ++j) {
        v[j] = (i0 + j < N) ? cnt[i0 + j] : 0;
        sum += v[j];
    }
    s[t] = sum;
    __syncthreads();
    for (int off = 1; off < 256; off <<= 1) {
        int add = (t >= off) ? s[t - off] : 0;
        __syncthreads();
        s[t] += add;
        __syncthreads();
    }
    int excl = s[t] - sum;
    #pragma unroll
    for (int j = 0; j < 4; ++j) {
        if (i0 + j < N) pos[i0 + j] = excl;
        excl += v[j];
    }
    if (t == 255) btot[blockIdx.x] = s[255];
}

__global__ __launch_bounds__(256) void scan_b(int* __restrict__ btot,
                                              int* __restrict__ bexcl,
                                              int NB) {
    __shared__ int s[256];
    const int t = threadIdx.x;
    const int own = (t < NB) ? btot[t] : 0;
    s[t] = own;
    __syncthreads();
    for (int off = 1; off < 256; off <<= 1) {
        int add = (t >= off) ? s[t - off] : 0;
        __syncthreads();
        s[t] += add;
        __syncthreads();
    }
    if (t < NB) bexcl[t] = s[t] - own;
}

__global__ __launch_bounds__(256) void scan_c(int* __restrict__ pos,
                                              const int* __restrict__ bexcl,
                                              int N) {
    const int add = bexcl[blockIdx.x];
    const int i0 = blockIdx.x * 1024 + threadIdx.x * 4;
    #pragma unroll
    for (int j = 0; j < 4; ++j) {
        if (i0 + j < N) pos[i0 + j] += add;
    }
}

// ---------------------------------------------------------------------------
// K5: permute edges into destination-sorted order; pack (row, nrm) into int2.
// After this kernel pos[n] = end offset of node n's segment.
// ---------------------------------------------------------------------------
__global__ __launch_bounds__(256) void permute(const int* __restrict__ ei,
                                               const float* __restrict__ ew,
                                               const float* __restrict__ deg,
                                               int* __restrict__ pos,
                                               int2* __restrict__ spk,
                                               int E) {
    const int e = blockIdx.x * 256 + threadIdx.x;
    if (e >= E) return;
    const int row = ei[e];
    const int col = ei[E + e];
    const float w = 1.f / (1.f + expf(-ew[e]));
    const float nrm = rsqrtf(deg[row] + 1.f) * w * rsqrtf(deg[col] + 1.f);
    const int p = atomicAdd(&pos[col], 1);
    int2 pk; pk.x = row; pk.y = __float_as_int(nrm);
    spk[p] = pk;
}

// ---------------------------------------------------------------------------
// K6: gather. 16 threads per node, float4 per thread (4 cols).
// out[n] = sum_edges xp[row]*nrm + xp[n]/(deg[n]+1) + bias
// ---------------------------------------------------------------------------
__global__ __launch_bounds__(256) void gather(const int2* __restrict__ spk,
                                              const int* __restrict__ pos,
                                              const int* __restrict__ cnt,
                                              const float* __restrict__ deg,
                                              const float* __restrict__ xp,
                                              const float* __restrict__ bias,
                                              float* __restrict__ out,
                                              int N) {
    const int t = threadIdx.x;
    const int ng = t >> 4;        // node within block, 0..15
    const int cg = t & 15;        // col group
    const int n = blockIdx.x * 16 + ng;
    if (n >= N) return;

    const int end = pos[n];
    const int c = cnt[n];
    const int s = end - c;

    const float4* xp4 = (const float4*)xp;
    float4 acc = make_float4(0.f, 0.f, 0.f, 0.f);
    for (int j = s; j < end; ++j) {
        const int2 pk = spk[j];
        const float nm = __int_as_float(pk.y);
        const float4 xv = xp4[(size_t)pk.x * 16 + cg];
        acc.x += xv.x * nm; acc.y += xv.y * nm;
        acc.z += xv.z * nm; acc.w += xv.w * nm;
    }
    const float dinv = 1.f / (deg[n] + 1.f);
    const float4 self = xp4[(size_t)n * 16 + cg];
    const float4 bv = ((const float4*)bias)[cg];
    float4 o;
    o.x = acc.x + self.x * dinv + bv.x;
    o.y = acc.y + self.y * dinv + bv.y;
    o.z = acc.z + self.z * dinv + bv.z;
    o.w = acc.w + self.w * dinv + bv.w;
    ((float4*)out)[(size_t)n * 16 + cg] = o;
}

// ---------------------------------------------------------------------------
extern "C" void kernel_launch(void* const* d_in, const int* in_sizes, int n_in,
                              void* d_out, int out_size, void* d_ws, size_t ws_size,
                              hipStream_t stream) {
    const float* x    = (const float*)d_in[0];
    const int*   ei   = (const int*)d_in[1];
    const float* W    = (const float*)d_in[2];
    const float* bias = (const float*)d_in[3];
    const float* ew   = (const float*)d_in[4];
    const float* u    = (const float*)d_in[5];
    float* out = (float*)d_out;

    const int N = in_sizes[0] / IN_DIM;   // 100000
    const int E = in_sizes[4];            // 600000
    const int NB = (N + 1023) / 1024;     // scan blocks (98)

    // Workspace layout (16B-aligned chunks):
    char* ws = (char*)d_ws;
    size_t off = 0;
    float* inv_sigma = (float*)(ws + off); off += 1024;
    float* deg  = (float*)(ws + off); off += (size_t)N * 4;       // zeroed
    int*   cnt  = (int*)  (ws + off); off += (size_t)N * 4;       // zeroed (contiguous with deg)
    int*   pos  = (int*)  (ws + off); off += (size_t)N * 4;
    int*   btot = (int*)  (ws + off); off += 4096;
    int*   bexcl= (int*)  (ws + off); off += 4096;
    int2*  spk  = (int2*) (ws + off); off += (size_t)E * 8;
    float* xp   = (float*)(ws + off); off += (size_t)N * OUT_DIM * 4;

    // zero deg + cnt in one shot (they are adjacent)
    hipMemsetAsync(deg, 0, (size_t)N * 8, stream);

    sigma_kernel<<<1, 128, 0, stream>>>(W, u, inv_sigma);
    edge_prep<<<(E + 255) / 256, 256, 0, stream>>>(ei, ew, deg, cnt, E);
    gemm_xp<<<(N + 63) / 64, 256, 0, stream>>>(x, W, inv_sigma, xp, N);
    scan_a<<<NB, 256, 0, stream>>>(cnt, pos, btot, N);
    scan_b<<<1, 256, 0, stream>>>(btot, bexcl, NB);
    scan_c<<<NB, 256, 0, stream>>>(pos, bexcl, N);
    permute<<<(E + 255) / 256, 256, 0, stream>>>(ei, ew, deg, pos, spk, E);
    gather<<<(N + 15) / 16, 256, 0, stream>>>(spk, pos, cnt, deg, xp, bias, out, N);
}

// Round 3
// 223.578 us; speedup vs baseline: 1.4591x; 1.2035x over previous
//
#include <hip/hip_runtime.h>
#include <math.h>

// GCNConv forward with spectral-norm weight scaling, CSR-gather formulation.
// x[N,128] f32, edge_index[2,E] int, W[128,64] f32, bias[64] f32,
// ew[E] f32, u[128] f32  ->  out[N,64] f32.   N=100000, E=600000.
//
// Pipeline (deterministic):
//   memset packed[N]=0
//   sigma      : inv_sigma = 1/sigma (power iteration step)
//   edge_prep  : ONE u64 atomic/edge: packed[col] += (1<<40)|fix32(w);
//                slot[e] = old>>40  (count in high 24 bits, fixed-point
//                weighted degree in low 40 bits)
//   gemm_xp    : xp = x @ (W*inv_sigma)
//   scan_a     : per-1024-block exclusive scan of counts -> pos, btot;
//                also unpack deg_f[n] = low40(packed[n]) * 2^-32
//   scan_b     : scan of block totals -> bexcl
//   permute    : spk[pos[col]+bexcl[col>>10]+slot[e]] = (row, nrm)  (no atomics)
//   gather     : out[n] = sum_seg xp[row]*nrm + xp[n]/(deg+1) + bias

#define IN_DIM 128
#define OUT_DIM 64

#define FIXSHIFT 4294967296.0   // 2^32
#define CNTSHIFT 40
#define DEGMASK  ((1ull << CNTSHIFT) - 1)

// ---------------------------------------------------------------------------
// K1: inv_sigma = 1/sigma, sigma from one power-iteration step.
// ---------------------------------------------------------------------------
__global__ __launch_bounds__(128) void sigma_kernel(const float* __restrict__ W,
                                                    const float* __restrict__ u,
                                                    float* __restrict__ inv_sigma) {
    __shared__ float v[OUT_DIM];
    __shared__ float red[128];
    const int t = threadIdx.x;

    // tv_half: j = t&63, i-range half = (t>>6)*64 .. +63
    {
        const int j = t & 63;
        const int ih = (t >> 6) * 64;
        float tv = 0.f;
        #pragma unroll 8
        for (int i = 0; i < 64; ++i) tv += W[(ih + i) * OUT_DIM + j] * u[ih + i];
        red[t] = tv;
    }
    __syncthreads();
    float tv = 0.f;
    if (t < OUT_DIM) tv = red[t] + red[t + 64];
    __syncthreads();
    red[t] = (t < OUT_DIM) ? tv * tv : 0.f;
    __syncthreads();
    for (int s = 64; s > 0; s >>= 1) {
        if (t < s) red[t] += red[t + s];
        __syncthreads();
    }
    const float nv = sqrtf(red[0]) + 1e-12f;
    __syncthreads();
    if (t < OUT_DIM) v[t] = tv / nv;
    __syncthreads();

    float wv = 0.f;
    #pragma unroll 8
    for (int j = 0; j < OUT_DIM; ++j) wv += W[t * OUT_DIM + j] * v[j];
    red[t] = wv * wv;
    __syncthreads();
    for (int s = 64; s > 0; s >>= 1) {
        if (t < s) red[t] += red[t + s];
        __syncthreads();
    }
    if (t == 0) {
        const float s2 = red[0];
        const float sn = sqrtf(s2);
        const float sigma = s2 / (sn + 1e-12f);
        inv_sigma[0] = 1.0f / sigma;
    }
}

// ---------------------------------------------------------------------------
// K2: single packed 64-bit atomic per edge.
// ---------------------------------------------------------------------------
__global__ __launch_bounds__(256) void edge_prep(const int* __restrict__ ei,
                                                 const float* __restrict__ ew,
                                                 unsigned long long* __restrict__ packed,
                                                 int* __restrict__ slot,
                                                 int E) {
    const int e = blockIdx.x * 256 + threadIdx.x;
    if (e >= E) return;
    const float w = 1.f / (1.f + expf(-ew[e]));
    const int col = ei[E + e];
    const unsigned long long inc =
        (1ull << CNTSHIFT) | (unsigned long long)((double)w * FIXSHIFT);
    const unsigned long long old = atomicAdd(&packed[col], inc);
    slot[e] = (int)(old >> CNTSHIFT);
}

// ---------------------------------------------------------------------------
// K3: xp = x @ (W * inv_sigma). Thread = 4 rows x 4 cols; block = 64 rows.
// ---------------------------------------------------------------------------
__global__ __launch_bounds__(256) void gemm_xp(const float* __restrict__ x,
                                               const float* __restrict__ W,
                                               const float* __restrict__ inv_sigma_p,
                                               float* __restrict__ xp,
                                               int N) {
    __shared__ float Wl[IN_DIM * OUT_DIM];   // 32 KB
    const int t = threadIdx.x;
    const float isg = inv_sigma_p[0];

    const float4* W4 = (const float4*)W;
    float4* Wl4 = (float4*)Wl;
    #pragma unroll
    for (int i = t; i < IN_DIM * OUT_DIM / 4; i += 256) {
        float4 wv = W4[i];
        wv.x *= isg; wv.y *= isg; wv.z *= isg; wv.w *= isg;
        Wl4[i] = wv;
    }
    __syncthreads();

    const int wave = t >> 6;
    const int lane = t & 63;
    const int rg = lane >> 4;
    const int cg = lane & 15;
    const int rowBase = blockIdx.x * 64 + wave * 16 + rg * 4;

    float4 acc[4];
    #pragma unroll
    for (int r = 0; r < 4; ++r) acc[r] = make_float4(0.f, 0.f, 0.f, 0.f);

    const float4* xg = (const float4*)x;
    #pragma unroll 4
    for (int kc = 0; kc < IN_DIM / 4; ++kc) {
        float4 wv0 = Wl4[(4 * kc + 0) * 16 + cg];
        float4 wv1 = Wl4[(4 * kc + 1) * 16 + cg];
        float4 wv2 = Wl4[(4 * kc + 2) * 16 + cg];
        float4 wv3 = Wl4[(4 * kc + 3) * 16 + cg];
        #pragma unroll
        for (int r = 0; r < 4; ++r) {
            const int row = min(rowBase + r, N - 1);
            const float4 xv = xg[(size_t)row * (IN_DIM / 4) + kc];
            acc[r].x += xv.x * wv0.x + xv.y * wv1.x + xv.z * wv2.x + xv.w * wv3.x;
            acc[r].y += xv.x * wv0.y + xv.y * wv1.y + xv.z * wv2.y + xv.w * wv3.y;
            acc[r].z += xv.x * wv0.z + xv.y * wv1.z + xv.z * wv2.z + xv.w * wv3.z;
            acc[r].w += xv.x * wv0.w + xv.y * wv1.w + xv.z * wv2.w + xv.w * wv3.w;
        }
    }

    float4* xp4 = (float4*)xp;
    #pragma unroll
    for (int r = 0; r < 4; ++r) {
        const int row = rowBase + r;
        if (row < N) xp4[(size_t)row * 16 + cg] = acc[r];
    }
}

// ---------------------------------------------------------------------------
// scan_a: per-block (1024 items) exclusive scan of counts; unpack deg.
// ---------------------------------------------------------------------------
__global__ __launch_bounds__(256) void scan_a(const unsigned long long* __restrict__ packed,
                                              int* __restrict__ pos,
                                              int* __restrict__ btot,
                                              float* __restrict__ deg_f,
                                              int N) {
    __shared__ int s[256];
    const int t = threadIdx.x;
    const int i0 = blockIdx.x * 1024 + t * 4;
    int v[4]; int sum = 0;
    #pragma unroll
    for (int j = 0; j < 4; ++j) {
        unsigned long long p = (i0 + j < N) ? packed[i0 + j] : 0ull;
        v[j] = (int)(p >> CNTSHIFT);
        sum += v[j];
        if (i0 + j < N)
            deg_f[i0 + j] = (float)((double)(p & DEGMASK) * (1.0 / FIXSHIFT));
    }
    s[t] = sum;
    __syncthreads();
    for (int off = 1; off < 256; off <<= 1) {
        int add = (t >= off) ? s[t - off] : 0;
        __syncthreads();
        s[t] += add;
        __syncthreads();
    }
    int excl = s[t] - sum;
    #pragma unroll
    for (int j = 0; j < 4; ++j) {
        if (i0 + j < N) pos[i0 + j] = excl;
        excl += v[j];
    }
    if (t == 255) btot[blockIdx.x] = s[255];
}

__global__ __launch_bounds__(256) void scan_b(const int* __restrict__ btot,
                                              int* __restrict__ bexcl,
                                              int NB) {
    __shared__ int s[256];
    const int t = threadIdx.x;
    const int own = (t < NB) ? btot[t] : 0;
    s[t] = own;
    __syncthreads();
    for (int off = 1; off < 256; off <<= 1) {
        int add = (t >= off) ? s[t - off] : 0;
        __syncthreads();
        s[t] += add;
        __syncthreads();
    }
    if (t < NB) bexcl[t] = s[t] - own;
}

// ---------------------------------------------------------------------------
// permute: place (row, nrm) at final sorted position. No atomics.
// ---------------------------------------------------------------------------
__global__ __launch_bounds__(256) void permute(const int* __restrict__ ei,
                                               const float* __restrict__ ew,
                                               const float* __restrict__ deg_f,
                                               const int* __restrict__ pos,
                                               const int* __restrict__ bexcl,
                                               const int* __restrict__ slot,
                                               int2* __restrict__ spk,
                                               int E) {
    const int e = blockIdx.x * 256 + threadIdx.x;
    if (e >= E) return;
    const int row = ei[e];
    const int col = ei[E + e];
    const float w = 1.f / (1.f + expf(-ew[e]));
    const float nrm = rsqrtf(deg_f[row] + 1.f) * w * rsqrtf(deg_f[col] + 1.f);
    const int p = pos[col] + bexcl[col >> 10] + slot[e];
    int2 pk; pk.x = row; pk.y = __float_as_int(nrm);
    spk[p] = pk;
}

// ---------------------------------------------------------------------------
// gather: 16 threads/node, float4/thread.
// ---------------------------------------------------------------------------
__global__ __launch_bounds__(256) void gather(const int2* __restrict__ spk,
                                              const int* __restrict__ pos,
                                              const int* __restrict__ bexcl,
                                              const unsigned long long* __restrict__ packed,
                                              const float* __restrict__ deg_f,
                                              const float* __restrict__ xp,
                                              const float* __restrict__ bias,
                                              float* __restrict__ out,
                                              int N) {
    const int t = threadIdx.x;
    const int ng = t >> 4;
    const int cg = t & 15;
    const int n = blockIdx.x * 16 + ng;
    if (n >= N) return;

    const int s = pos[n] + bexcl[n >> 10];
    const int c = (int)(packed[n] >> CNTSHIFT);
    const int end = s + c;

    const float4* xp4 = (const float4*)xp;
    float4 acc = make_float4(0.f, 0.f, 0.f, 0.f);
    for (int j = s; j < end; ++j) {
        const int2 pk = spk[j];
        const float nm = __int_as_float(pk.y);
        const float4 xv = xp4[(size_t)pk.x * 16 + cg];
        acc.x += xv.x * nm; acc.y += xv.y * nm;
        acc.z += xv.z * nm; acc.w += xv.w * nm;
    }
    const float dinv = 1.f / (deg_f[n] + 1.f);
    const float4 self = xp4[(size_t)n * 16 + cg];
    const float4 bv = ((const float4*)bias)[cg];
    float4 o;
    o.x = acc.x + self.x * dinv + bv.x;
    o.y = acc.y + self.y * dinv + bv.y;
    o.z = acc.z + self.z * dinv + bv.z;
    o.w = acc.w + self.w * dinv + bv.w;
    ((float4*)out)[(size_t)n * 16 + cg] = o;
}

// ---------------------------------------------------------------------------
extern "C" void kernel_launch(void* const* d_in, const int* in_sizes, int n_in,
                              void* d_out, int out_size, void* d_ws, size_t ws_size,
                              hipStream_t stream) {
    const float* x    = (const float*)d_in[0];
    const int*   ei   = (const int*)d_in[1];
    const float* W    = (const float*)d_in[2];
    const float* bias = (const float*)d_in[3];
    const float* ew   = (const float*)d_in[4];
    const float* u    = (const float*)d_in[5];
    float* out = (float*)d_out;

    const int N = in_sizes[0] / IN_DIM;   // 100000
    const int E = in_sizes[4];            // 600000
    const int NB = (N + 1023) / 1024;     // 98 scan blocks (<=256)

    char* ws = (char*)d_ws;
    size_t off = 0;
    float* inv_sigma = (float*)(ws + off); off += 1024;
    unsigned long long* packed = (unsigned long long*)(ws + off); off += (size_t)N * 8;
    int*   slot = (int*)  (ws + off); off += (size_t)E * 4;
    int*   pos  = (int*)  (ws + off); off += (size_t)N * 4;
    int*   btot = (int*)  (ws + off); off += 4096;
    int*   bexcl= (int*)  (ws + off); off += 4096;
    float* deg_f= (float*)(ws + off); off += (size_t)N * 4;
    int2*  spk  = (int2*) (ws + off); off += (size_t)E * 8;
    float* xp   = (float*)(ws + off); off += (size_t)N * OUT_DIM * 4;

    hipMemsetAsync(packed, 0, (size_t)N * 8, stream);
    sigma_kernel<<<1, 128, 0, stream>>>(W, u, inv_sigma);
    edge_prep<<<(E + 255) / 256, 256, 0, stream>>>(ei, ew, packed, slot, E);
    gemm_xp<<<(N + 63) / 64, 256, 0, stream>>>(x, W, inv_sigma, xp, N);
    scan_a<<<NB, 256, 0, stream>>>(packed, pos, btot, deg_f, N);
    scan_b<<<1, 256, 0, stream>>>(btot, bexcl, NB);
    permute<<<(E + 255) / 256, 256, 0, stream>>>(ei, ew, deg_f, pos, bexcl, slot, spk, E);
    gather<<<(N + 15) / 16, 256, 0, stream>>>(spk, pos, bexcl, packed, deg_f, xp, bias, out, N);
}

// Round 4
// 220.556 us; speedup vs baseline: 1.4791x; 1.0137x over previous
//
#include <hip/hip_runtime.h>
#include <math.h>

// GCNConv forward with spectral-norm weight scaling, CSR-gather formulation.
// x[N,128] f32, edge_index[2,E] int, W[128,64] f32, bias[64] f32,
// ew[E] f32, u[128] f32  ->  out[N,64] f32.   N=100000, E=600000.
//
// Pipeline (5 dispatches, deterministic):
//   memset packed[N]=0
//   fused_A : blocks [0,G)   = sigma (per-block) + gemm  xp = x@(W/sigma)
//                              (thread = 1 row x 64 cols, W broadcast from LDS)
//             blocks [G,G+EB)= edge_prep: ONE u64 atomic/edge:
//                              packed[col] += (1<<40)|fix32(sigmoid(ew));
//                              slot[e] = old>>40
//             The two halves are independent and overlap (VALU vs atomic pipes).
//   scan_a  : per-1024 exclusive scan of counts -> pos, btot; unpack deg_f
//   permute : inline-scan btot -> bexcl (LDS); spk[pos+bexcl+slot] = (row,nrm)
//   gather  : inline-scan btot; out[n] = sum_seg xp[row]*nrm + xp[n]/(deg+1)+bias

#define IN_DIM 128
#define OUT_DIM 64

#define FIXSHIFT 4294967296.0   // 2^32
#define CNTSHIFT 40
#define DEGMASK  ((1ull << CNTSHIFT) - 1)

// ---------------------------------------------------------------------------
// fused kernel A
// ---------------------------------------------------------------------------
__global__ __launch_bounds__(256, 4) void fused_A(const float* __restrict__ x,
                                                  const float* __restrict__ W,
                                                  const float* __restrict__ u,
                                                  const int* __restrict__ ei,
                                                  const float* __restrict__ ew,
                                                  unsigned long long* __restrict__ packed,
                                                  int* __restrict__ slot,
                                                  float* __restrict__ xp,
                                                  int N, int E, int G) {
    const int t = threadIdx.x;

    if ((int)blockIdx.x >= G) {
        // ---------------- edge_prep path ----------------
        const int e = ((int)blockIdx.x - G) * 256 + t;
        if (e < E) {
            const float w = 1.f / (1.f + expf(-ew[e]));
            const int col = ei[E + e];
            const unsigned long long inc =
                (1ull << CNTSHIFT) | (unsigned long long)((double)w * FIXSHIFT);
            const unsigned long long old = atomicAdd(&packed[col], inc);
            slot[e] = (int)(old >> CNTSHIFT);
        }
        return;
    }

    // ---------------- sigma + gemm path ----------------
    __shared__ float Wl[IN_DIM * OUT_DIM];   // 32 KB
    __shared__ float red[256];
    __shared__ float vsh[OUT_DIM];
    __shared__ float s_isg;

    // --- sigma: v = norm(W^T u); sigma = ||Wv||^2/(||Wv||+eps) ---
    {
        const int j = t & 63;
        const int i0 = (t >> 6) * 32;
        float tv = 0.f;
        #pragma unroll 8
        for (int i = 0; i < 32; ++i) tv += W[(i0 + i) * OUT_DIM + j] * u[i0 + i];
        red[t] = tv;
    }
    __syncthreads();
    float tvj = 0.f;
    if (t < 64) tvj = red[t] + red[t + 64] + red[t + 128] + red[t + 192];
    __syncthreads();
    red[t] = (t < 64) ? tvj * tvj : 0.f;
    __syncthreads();
    for (int s = 128; s > 0; s >>= 1) {
        if (t < s) red[t] += red[t + s];
        __syncthreads();
    }
    const float nv = sqrtf(red[0]) + 1e-12f;
    __syncthreads();
    if (t < 64) vsh[t] = tvj / nv;
    __syncthreads();
    float wv = 0.f;
    if (t < 128) {
        #pragma unroll 8
        for (int j = 0; j < OUT_DIM; ++j) wv += W[t * OUT_DIM + j] * vsh[j];
    }
    red[t] = (t < 128) ? wv * wv : 0.f;
    __syncthreads();
    for (int s = 128; s > 0; s >>= 1) {
        if (t < s) red[t] += red[t + s];
        __syncthreads();
    }
    if (t == 0) {
        const float s2 = red[0];
        const float sn = sqrtf(s2);
        const float sigma = s2 / (sn + 1e-12f);
        s_isg = 1.0f / sigma;
    }
    __syncthreads();
    const float isg = s_isg;

    // --- load scaled W into LDS ---
    {
        const float4* W4 = (const float4*)W;
        float4* Wl4 = (float4*)Wl;
        #pragma unroll
        for (int i = t; i < IN_DIM * OUT_DIM / 4; i += 256) {
            float4 w4 = W4[i];
            w4.x *= isg; w4.y *= isg; w4.z *= isg; w4.w *= isg;
            Wl4[i] = w4;
        }
    }
    __syncthreads();

    // --- gemm: thread = one row, 64 output cols in registers ---
    const int row = (int)blockIdx.x * 256 + t;
    const int rc = min(row, N - 1);

    float acc[OUT_DIM];
    #pragma unroll
    for (int c = 0; c < OUT_DIM; ++c) acc[c] = 0.f;

    const float4* xg = (const float4*)x;
    for (int kc = 0; kc < IN_DIM / 4; ++kc) {
        const float4 xv = xg[(size_t)rc * (IN_DIM / 4) + kc];
        const float* wrow = &Wl[kc * 4 * OUT_DIM];
        #pragma unroll
        for (int j = 0; j < 16; ++j) {
            const float4 w0 = *(const float4*)&wrow[0 * OUT_DIM + 4 * j];
            const float4 w1 = *(const float4*)&wrow[1 * OUT_DIM + 4 * j];
            const float4 w2 = *(const float4*)&wrow[2 * OUT_DIM + 4 * j];
            const float4 w3 = *(const float4*)&wrow[3 * OUT_DIM + 4 * j];
            acc[4 * j + 0] += xv.x * w0.x + xv.y * w1.x + xv.z * w2.x + xv.w * w3.x;
            acc[4 * j + 1] += xv.x * w0.y + xv.y * w1.y + xv.z * w2.y + xv.w * w3.y;
            acc[4 * j + 2] += xv.x * w0.z + xv.y * w1.z + xv.z * w2.z + xv.w * w3.z;
            acc[4 * j + 3] += xv.x * w0.w + xv.y * w1.w + xv.z * w2.w + xv.w * w3.w;
        }
    }

    if (row < N) {
        float4* xp4 = (float4*)xp;
        #pragma unroll
        for (int j = 0; j < 16; ++j) {
            xp4[(size_t)row * 16 + j] =
                make_float4(acc[4 * j + 0], acc[4 * j + 1], acc[4 * j + 2], acc[4 * j + 3]);
        }
    }
}

// ---------------------------------------------------------------------------
// scan_a: per-block (1024 items) exclusive scan of counts; unpack deg.
// ---------------------------------------------------------------------------
__global__ __launch_bounds__(256) void scan_a(const unsigned long long* __restrict__ packed,
                                              int* __restrict__ pos,
                                              int* __restrict__ btot,
                                              float* __restrict__ deg_f,
                                              int N) {
    __shared__ int s[256];
    const int t = threadIdx.x;
    const int i0 = blockIdx.x * 1024 + t * 4;
    int v[4]; int sum = 0;
    #pragma unroll
    for (int j = 0; j < 4; ++j) {
        unsigned long long p = (i0 + j < N) ? packed[i0 + j] : 0ull;
        v[j] = (int)(p >> CNTSHIFT);
        sum += v[j];
        if (i0 + j < N)
            deg_f[i0 + j] = (float)((double)(p & DEGMASK) * (1.0 / FIXSHIFT));
    }
    s[t] = sum;
    __syncthreads();
    for (int off = 1; off < 256; off <<= 1) {
        int add = (t >= off) ? s[t - off] : 0;
        __syncthreads();
        s[t] += add;
        __syncthreads();
    }
    int excl = s[t] - sum;
    #pragma unroll
    for (int j = 0; j < 4; ++j) {
        if (i0 + j < N) pos[i0 + j] = excl;
        excl += v[j];
    }
    if (t == 255) btot[blockIdx.x] = s[255];
}

// ---------------------------------------------------------------------------
// permute: inline scan of btot -> bexcl in LDS; place (row, nrm). No atomics.
// ---------------------------------------------------------------------------
__global__ __launch_bounds__(256) void permute(const int* __restrict__ ei,
                                               const float* __restrict__ ew,
                                               const float* __restrict__ deg_f,
                                               const int* __restrict__ pos,
                                               const int* __restrict__ btot,
                                               const int* __restrict__ slot,
                                               int2* __restrict__ spk,
                                               int E, int NB) {
    __shared__ int s[256];
    __shared__ int bex[256];
    const int t = threadIdx.x;
    const int own = (t < NB) ? btot[t] : 0;
    s[t] = own;
    __syncthreads();
    for (int off = 1; off < 256; off <<= 1) {
        int add = (t >= off) ? s[t - off] : 0;
        __syncthreads();
        s[t] += add;
        __syncthreads();
    }
    bex[t] = s[t] - own;
    __syncthreads();

    const int e = blockIdx.x * 256 + t;
    if (e >= E) return;
    const int row = ei[e];
    const int col = ei[E + e];
    const float w = 1.f / (1.f + expf(-ew[e]));
    const float nrm = rsqrtf(deg_f[row] + 1.f) * w * rsqrtf(deg_f[col] + 1.f);
    const int p = pos[col] + bex[col >> 10] + slot[e];
    int2 pk; pk.x = row; pk.y = __float_as_int(nrm);
    spk[p] = pk;
}

// ---------------------------------------------------------------------------
// gather: inline scan of btot; 16 threads/node, float4/thread, 2-way unroll.
// ---------------------------------------------------------------------------
__global__ __launch_bounds__(256) void gather(const int2* __restrict__ spk,
                                              const int* __restrict__ pos,
                                              const int* __restrict__ btot,
                                              const unsigned long long* __restrict__ packed,
                                              const float* __restrict__ deg_f,
                                              const float* __restrict__ xp,
                                              const float* __restrict__ bias,
                                              float* __restrict__ out,
                                              int N, int NB) {
    __shared__ int s[256];
    __shared__ int bex[256];
    const int t = threadIdx.x;
    const int own = (t < NB) ? btot[t] : 0;
    s[t] = own;
    __syncthreads();
    for (int off = 1; off < 256; off <<= 1) {
        int add = (t >= off) ? s[t - off] : 0;
        __syncthreads();
        s[t] += add;
        __syncthreads();
    }
    bex[t] = s[t] - own;
    __syncthreads();

    const int ng = t >> 4;
    const int cg = t & 15;
    const int n = blockIdx.x * 16 + ng;
    if (n >= N) return;

    const int st = pos[n] + bex[n >> 10];
    const int c = (int)(packed[n] >> CNTSHIFT);
    const int end = st + c;

    const float4* xp4 = (const float4*)xp;
    float4 acc0 = make_float4(0.f, 0.f, 0.f, 0.f);
    float4 acc1 = make_float4(0.f, 0.f, 0.f, 0.f);
    int j = st;
    for (; j + 1 < end; j += 2) {
        const int2 pk0 = spk[j];
        const int2 pk1 = spk[j + 1];
        const float nm0 = __int_as_float(pk0.y);
        const float nm1 = __int_as_float(pk1.y);
        const float4 xv0 = xp4[(size_t)pk0.x * 16 + cg];
        const float4 xv1 = xp4[(size_t)pk1.x * 16 + cg];
        acc0.x += xv0.x * nm0; acc0.y += xv0.y * nm0;
        acc0.z += xv0.z * nm0; acc0.w += xv0.w * nm0;
        acc1.x += xv1.x * nm1; acc1.y += xv1.y * nm1;
        acc1.z += xv1.z * nm1; acc1.w += xv1.w * nm1;
    }
    if (j < end) {
        const int2 pk = spk[j];
        const float nm = __int_as_float(pk.y);
        const float4 xv = xp4[(size_t)pk.x * 16 + cg];
        acc0.x += xv.x * nm; acc0.y += xv.y * nm;
        acc0.z += xv.z * nm; acc0.w += xv.w * nm;
    }
    const float dinv = 1.f / (deg_f[n] + 1.f);
    const float4 self = xp4[(size_t)n * 16 + cg];
    const float4 bv = ((const float4*)bias)[cg];
    float4 o;
    o.x = acc0.x + acc1.x + self.x * dinv + bv.x;
    o.y = acc0.y + acc1.y + self.y * dinv + bv.y;
    o.z = acc0.z + acc1.z + self.z * dinv + bv.z;
    o.w = acc0.w + acc1.w + self.w * dinv + bv.w;
    ((float4*)out)[(size_t)n * 16 + cg] = o;
}

// ---------------------------------------------------------------------------
extern "C" void kernel_launch(void* const* d_in, const int* in_sizes, int n_in,
                              void* d_out, int out_size, void* d_ws, size_t ws_size,
                              hipStream_t stream) {
    const float* x    = (const float*)d_in[0];
    const int*   ei   = (const int*)d_in[1];
    const float* W    = (const float*)d_in[2];
    const float* bias = (const float*)d_in[3];
    const float* ew   = (const float*)d_in[4];
    const float* u    = (const float*)d_in[5];
    float* out = (float*)d_out;

    const int N = in_sizes[0] / IN_DIM;   // 100000
    const int E = in_sizes[4];            // 600000
    const int NB = (N + 1023) / 1024;     // 98 scan blocks (<=256)
    const int G  = (N + 255) / 256;       // gemm blocks (391)
    const int EB = (E + 255) / 256;       // edge blocks (2344)

    char* ws = (char*)d_ws;
    size_t off = 0;
    unsigned long long* packed = (unsigned long long*)(ws + off); off += (size_t)N * 8;
    int*   slot = (int*)  (ws + off); off += (size_t)E * 4;
    int*   pos  = (int*)  (ws + off); off += (size_t)N * 4;
    int*   btot = (int*)  (ws + off); off += 4096;
    float* deg_f= (float*)(ws + off); off += (size_t)N * 4;
    int2*  spk  = (int2*) (ws + off); off += (size_t)E * 8;
    float* xp   = (float*)(ws + off); off += (size_t)N * OUT_DIM * 4;

    hipMemsetAsync(packed, 0, (size_t)N * 8, stream);
    fused_A<<<G + EB, 256, 0, stream>>>(x, W, u, ei, ew, packed, slot, xp, N, E, G);
    scan_a<<<NB, 256, 0, stream>>>(packed, pos, btot, deg_f, N);
    permute<<<EB, 256, 0, stream>>>(ei, ew, deg_f, pos, btot, slot, spk, E, NB);
    gather<<<(N + 15) / 16, 256, 0, stream>>>(spk, pos, btot, packed, deg_f, xp, bias, out, N, NB);
}